// Round 10
// baseline (182.324 us; speedup 1.0000x reference)
//
#include <hip/hip_runtime.h>

#define BATCH 8
#define SEQ   8192
#define NH    16
#define DP    64
#define DN    64
#define ROWF  (NH*DP)        // 1024 floats per t (all heads)
#define HGRP  4              // heads per block (contiguous 1KB quarter-row)
#define NTHR  256            // 4 waves; wave w <-> head hg*4+w
#define TROWS 8              // t-rows staged per tile (8 x 1KB per array)

typedef const __attribute__((address_space(1))) void* gptr_t;
typedef __attribute__((address_space(3))) void* lptr_t;

// ---------------------------------------------------------------------------
// k_partial: block = (b, head-group of 4, chunk). Each wave owns the full
// 64x64 state of ONE head. 256-thread blocks, 32KB LDS -> 4 blocks/CU.
// partial[p][n] = sum_t exp(chunkTotal - cumsum_t) * X[t][p] * B[t][n]
// ---------------------------------------------------------------------------
template<int NBLK>
__global__ __launch_bounds__(NTHR)
// LAUNCH-BOUNDS LAW on this toolchain (rounds 1,2,3,5,6,8): the 2nd arg pins
// waves/EU to EXACTLY arg (occupancy ceiling = arg/8) AND caps VGPR:
//   arg=4 -> 64-VGPR cap -> acc[8][8] spills (+340..470MB WRITE, 1.3-2.5x slow)
//   arg=2 -> no spill (VGPR 72-112) but occupancy pinned to 25% (r8: 24.6%)
// NO 2nd arg -> natural allocation (72 VGPR, r8) + no occupancy ceiling:
// 4 waves/EU by VGPR, 5 blocks by LDS, grid provides 4 blocks/CU.
void k_partial(const float* __restrict__ Xg, const float* __restrict__ Ag,
               const float* __restrict__ Bg, float* __restrict__ part,
               float* __restrict__ blockA)
{
    constexpr int TB    = SEQ / NBLK;   // 256 (NBLK=32) or 512 (NBLK=16)
    constexpr int Q     = TB / 64;      // A-values per lane in the scan: 4 or 8
    constexpr int NTILE = TB / TROWS;   // 32 or 64

    __shared__ float sX[2][TROWS][HGRP * DP];   // 16 KB
    __shared__ float sB[2][TROWS][HGRP * DP];   // 16 KB (total 32 KB -> 4 blk/CU)

    const int gid  = blockIdx.x;             // b*(4*NBLK) + hg*NBLK + blk
    const int blk  = gid % NBLK;
    const int hg   = (gid / NBLK) & 3;
    const int b    = gid / (4 * NBLK);
    const int tid  = threadIdx.x;
    const int wave = tid >> 6;               // 0..3
    const int lane = tid & 63;
    const int h    = hg * HGRP + wave;
    const int t0   = blk * TB;

    // ---- per-wave scan of A column h over this chunk (lane holds Q consecutive t)
    float c[Q];
    {
        const size_t abase = ((size_t)(b * SEQ + t0 + lane * Q)) * NH + h;
        float run = 0.f;
        #pragma unroll
        for (int k = 0; k < Q; ++k) { run += Ag[abase + (size_t)k * NH]; c[k] = run; }
    }
    float tsum = c[Q - 1], s = tsum;
    #pragma unroll
    for (int d = 1; d < 64; d <<= 1) {
        float o = __shfl_up(s, d, 64);
        if (lane >= d) s += o;
    }
    const float total = __shfl(s, 63, 64);
    const float excl  = s - tsum;            // exclusive prefix of this lane
    float wv[Q];                             // weights stay in registers
    #pragma unroll
    for (int k = 0; k < Q; ++k) wv[k] = __expf(total - (excl + c[k]));
    if (lane == 63) blockA[(size_t)(b * NH + h) * NBLK + blk] = total;

    // ---- main loop
    float acc[8][8];
    #pragma unroll
    for (int i = 0; i < 8; ++i)
        #pragma unroll
        for (int j = 0; j < 8; ++j) acc[i][j] = 0.f;

    const int p0F = (lane >> 3) << 3;        // 8x8 per-lane tile of the 64x64 state
    const int n0F = (lane & 7) << 3;
    const int lo16 = lane * 4;               // this lane's 16B within a 1KB segment
    const size_t xrow0 = ((size_t)(b * SEQ + t0)) * ROWF + hg * (HGRP * DP);

    auto stage = [&](int tile, int buf) {    // wave w stages rows {2w, 2w+1}
        #pragma unroll
        for (int r2 = 0; r2 < 2; ++r2) {
            const int row = wave * 2 + r2;                 // 0..7
            const size_t rb = xrow0 + (size_t)(tile * TROWS + row) * ROWF + lo16;
            __builtin_amdgcn_global_load_lds((gptr_t)(Xg + rb),
                                             (lptr_t)&sX[buf][row][0], 16, 0, 0);
            __builtin_amdgcn_global_load_lds((gptr_t)(Bg + rb),
                                             (lptr_t)&sB[buf][row][0], 16, 0, 0);
        }
    };

    stage(0, 0);
    for (int tile = 0; tile < NTILE; ++tile) {
        const int buf = tile & 1;
        // (A) all 4 waves finished reading buf^1 before we overwrite it
        asm volatile("s_waitcnt lgkmcnt(0)" ::: "memory");
        __builtin_amdgcn_s_barrier();
        stage((tile + 1) % NTILE, buf ^ 1);            // wrap on last iter (unread)
        // wait own 4 loads of CURRENT tile; next tile's 4 stay in flight
        asm volatile("s_waitcnt vmcnt(4)" ::: "memory");
        __builtin_amdgcn_s_barrier();                  // (B) tile rows visible to all

        #pragma unroll
        for (int tt = 0; tt < TROWS; ++tt) {
            const int tglob = tile * TROWS + tt;
            const int srcl  = tglob / Q;                       // uniform lane index
            const float wt  = __shfl(wv[tt & (Q - 1)], srcl, 64);
            const float* rx = &sX[buf][tt][wave * 64];
            const float* rbp = &sB[buf][tt][wave * 64];
            const float4 xa = *(const float4*)&rx[p0F];
            const float4 xb = *(const float4*)&rx[p0F + 4];
            const float4 ba = *(const float4*)&rbp[n0F];
            const float4 bb = *(const float4*)&rbp[n0F + 4];
            const float xs[8] = { xa.x * wt, xa.y * wt, xa.z * wt, xa.w * wt,
                                  xb.x * wt, xb.y * wt, xb.z * wt, xb.w * wt };
            const float bs[8] = { ba.x, ba.y, ba.z, ba.w, bb.x, bb.y, bb.z, bb.w };
            #pragma unroll
            for (int i = 0; i < 8; ++i)
                #pragma unroll
                for (int j = 0; j < 8; ++j)
                    acc[i][j] = fmaf(xs[i], bs[j], acc[i][j]);
        }
    }

    // ---- epilogue: acc rows are n-contiguous -> float4 stores
    float* dst = part + ((size_t)(b * NH + h) * NBLK + blk) * 4096;
    #pragma unroll
    for (int i = 0; i < 8; ++i) {
        float4 lo = make_float4(acc[i][0], acc[i][1], acc[i][2], acc[i][3]);
        float4 hi = make_float4(acc[i][4], acc[i][5], acc[i][6], acc[i][7]);
        *(float4*)&dst[(p0F + i) * 64 + n0F]     = lo;
        *(float4*)&dst[(p0F + i) * 64 + n0F + 4] = hi;
    }
}

// ---------------------------------------------------------------------------
// k_scales: suffix-exp over chunk totals, per (b,h)
// ---------------------------------------------------------------------------
__global__ void k_scales(const float* __restrict__ blockA, float* __restrict__ scale,
                         int nblk)
{
    const int bh = blockIdx.x * blockDim.x + threadIdx.x;
    if (bh < BATCH * NH) {
        float run = 0.f;
        for (int c2 = nblk - 1; c2 >= 0; --c2) {
            scale[bh * nblk + c2] = __expf(run);
            run += blockA[bh * nblk + c2];
        }
    }
}

// ---------------------------------------------------------------------------
// k_combine: out[bh,p,n] = sum_c scale[bh,c] * part[bh,c,p,n]
// ---------------------------------------------------------------------------
__global__ __launch_bounds__(256)
void k_combine(const float* __restrict__ part, const float* __restrict__ scale,
               float* __restrict__ out, int nblk)
{
    const int idx = blockIdx.x * 256 + threadIdx.x;   // 0..524287
    const int bh  = idx >> 12;
    const int e   = idx & 4095;
    float r = 0.f;
    for (int q = 0; q < nblk; ++q)
        r += scale[bh * nblk + q] * part[((size_t)bh * nblk + q) * 4096 + e];
    out[idx] = r;
}

// ---------------------------------------------------------------------------
extern "C" void kernel_launch(void* const* d_in, const int* in_sizes, int n_in,
                              void* d_out, int out_size, void* d_ws, size_t ws_size,
                              hipStream_t stream)
{
    const float* X = (const float*)d_in[0];
    const float* A = (const float*)d_in[1];
    const float* B = (const float*)d_in[2];
    float* out     = (float*)d_out;

    // ws need for NBLK chunks: part (8*16*NBLK*4096 f32) + blockA + scale
    const size_t need32 = ((size_t)BATCH * NH * 32 * 4096 + 2ull * BATCH * NH * 32) * 4;
    const int nblk = (ws_size >= need32) ? 32 : 16;

    float* part   = (float*)d_ws;
    float* blockA = part + (size_t)BATCH * NH * nblk * 4096;
    float* scale  = blockA + (size_t)BATCH * NH * nblk;

    if (nblk == 32)
        hipLaunchKernelGGL((k_partial<32>), dim3(BATCH * 4 * 32), dim3(NTHR), 0, stream,
                           X, A, B, part, blockA);
    else
        hipLaunchKernelGGL((k_partial<16>), dim3(BATCH * 4 * 16), dim3(NTHR), 0, stream,
                           X, A, B, part, blockA);

    hipLaunchKernelGGL(k_scales, dim3(1), dim3(128), 0, stream, blockA, scale, nblk);
    hipLaunchKernelGGL(k_combine, dim3((BATCH * NH * 4096) / 256), dim3(256), 0, stream,
                       part, scale, out, nblk);
}

// Round 11
// 179.724 us; speedup vs baseline: 1.0145x; 1.0145x over previous
//
#include <hip/hip_runtime.h>

#define BATCH 8
#define SEQ   8192
#define NH    16
#define DP    64
#define DN    64
#define ROWF  (NH*DP)        // 1024 floats per t (all heads)
#define HGRP  4              // heads per block (contiguous 1KB quarter-row)
#define NTHR  256            // 4 waves; wave w <-> head hg*4+w
#define TROWS 8              // t-rows staged per tile (8 x 1KB per array)

// ---------------------------------------------------------------------------
// k_partial: block = (b, head-group of 4, chunk). Each wave owns the 64x64
// state of ONE head. REG-STAGED pipeline (T14): plain global_load_dwordx4 ->
// VGPRs issued 2 tiles ahead (deep VMEM queue), ds_write_b128 -> LDS after
// compute, ONE barrier per tile. Replaces global_load_lds whose 4-8
// outstanding wave-loads pinned every prior variant at ~7600 cyc/tile
// (rounds 2,5,8,10 all ~200us at 1.4-1.7 TB/s regardless of occupancy).
// partial[p][n] = sum_t exp(chunkTotal - cumsum_t) * X[t][p] * B[t][n]
// ---------------------------------------------------------------------------
template<int NBLK>
__global__ __launch_bounds__(NTHR)
void k_partial(const float* __restrict__ Xg, const float* __restrict__ Ag,
               const float* __restrict__ Bg, float* __restrict__ part,
               float* __restrict__ blockA)
{
    constexpr int TB    = SEQ / NBLK;   // 256 (NBLK=32) or 512 (NBLK=16)
    constexpr int Q     = TB / 64;      // A-values per lane in the scan
    constexpr int NTILE = TB / TROWS;   // 32 or 64

    __shared__ float sX[2][TROWS][HGRP * DP];   // 16 KB
    __shared__ float sB[2][TROWS][HGRP * DP];   // 16 KB (32 KB total -> 4 blk/CU)

    const int gid  = blockIdx.x;             // b*(4*NBLK) + hg*NBLK + blk
    const int blk  = gid % NBLK;
    const int hg   = (gid / NBLK) & 3;
    const int b    = gid / (4 * NBLK);
    const int tid  = threadIdx.x;
    const int wave = tid >> 6;               // 0..3
    const int lane = tid & 63;
    const int h    = hg * HGRP + wave;
    const int t0   = blk * TB;

    // ---- per-wave scan of A column h over this chunk ----
    float c[Q];
    {
        const size_t abase = ((size_t)(b * SEQ + t0 + lane * Q)) * NH + h;
        float run = 0.f;
        #pragma unroll
        for (int k = 0; k < Q; ++k) { run += Ag[abase + (size_t)k * NH]; c[k] = run; }
    }
    float tsum = c[Q - 1], s = tsum;
    #pragma unroll
    for (int d = 1; d < 64; d <<= 1) {
        float o = __shfl_up(s, d, 64);
        if (lane >= d) s += o;
    }
    const float total = __shfl(s, 63, 64);
    const float excl  = s - tsum;
    float wv[Q];
    #pragma unroll
    for (int k = 0; k < Q; ++k) wv[k] = __expf(total - (excl + c[k]));
    if (lane == 63) blockA[(size_t)(b * NH + h) * NBLK + blk] = total;

    // ---- accumulator ----
    float acc[8][8];
    #pragma unroll
    for (int i = 0; i < 8; ++i)
        #pragma unroll
        for (int j = 0; j < 8; ++j) acc[i][j] = 0.f;

    const int p0F = (lane >> 3) << 3;
    const int n0F = (lane & 7) << 3;
    const int lo4 = lane * 4;               // float offset of lane's 16B in a 1KB row
    const int r0  = wave * 2;               // this wave's two staged rows
    const size_t xrow0 = ((size_t)(b * SEQ + t0)) * ROWF + hg * (HGRP * DP);

    // issue 4 coalesced 1KB wave-loads (rows r0,r0+1 of X and B) into regs
    auto gload = [&](int tile, float4& x0, float4& x1, float4& b0, float4& b1) {
        const int tt = tile % NTILE;                     // clamp wrap (prefetch tail)
        const size_t rb = xrow0 + (size_t)(tt * TROWS + r0) * ROWF + lo4;
        x0 = *(const float4*)(Xg + rb);
        x1 = *(const float4*)(Xg + rb + ROWF);
        b0 = *(const float4*)(Bg + rb);
        b1 = *(const float4*)(Bg + rb + ROWF);
    };
    // write regset into LDS buffer (compiler inserts the vmcnt wait here)
    auto lwrite = [&](int buf, const float4& x0, const float4& x1,
                      const float4& b0, const float4& b1) {
        *(float4*)&sX[buf][r0][lo4]     = x0;
        *(float4*)&sX[buf][r0 + 1][lo4] = x1;
        *(float4*)&sB[buf][r0][lo4]     = b0;
        *(float4*)&sB[buf][r0 + 1][lo4] = b1;
    };
    auto compute = [&](int buf, int tile) {
        #pragma unroll
        for (int tt = 0; tt < TROWS; ++tt) {
            const int tglob = tile * TROWS + tt;
            const int srcl  = tglob / Q;                       // uniform lane index
            const float wt  = __shfl(wv[tt & (Q - 1)], srcl, 64);
            const float* rx  = &sX[buf][tt][wave * 64];
            const float* rbp = &sB[buf][tt][wave * 64];
            const float4 xa = *(const float4*)&rx[p0F];
            const float4 xb = *(const float4*)&rx[p0F + 4];
            const float4 ba = *(const float4*)&rbp[n0F];
            const float4 bb = *(const float4*)&rbp[n0F + 4];
            const float xs[8] = { xa.x * wt, xa.y * wt, xa.z * wt, xa.w * wt,
                                  xb.x * wt, xb.y * wt, xb.z * wt, xb.w * wt };
            const float bs[8] = { ba.x, ba.y, ba.z, ba.w, bb.x, bb.y, bb.z, bb.w };
            #pragma unroll
            for (int i = 0; i < 8; ++i)
                #pragma unroll
                for (int j = 0; j < 8; ++j)
                    acc[i][j] = fmaf(xs[i], bs[j], acc[i][j]);
        }
    };

    // ---- software pipeline: 2 named regsets (static indexing only, rule #20),
    // LDS double buffer, one barrier per tile.
    float4 ax0, ax1, ab0, ab1;     // regset A
    float4 bx0, bx1, bb0, bb1;     // regset B

    gload(0, ax0, ax1, ab0, ab1);
    gload(1, bx0, bx1, bb0, bb1);
    lwrite(0, ax0, ax1, ab0, ab1);                 // waits A-set loads
    asm volatile("s_waitcnt lgkmcnt(0)" ::: "memory");
    __builtin_amdgcn_s_barrier();                  // LDS0 = tile 0 visible

    for (int kk = 0; kk < NTILE; kk += 2) {
        // tile kk: LDS0 current; A-regs free
        gload(kk + 2, ax0, ax1, ab0, ab1);         // 2-ahead prefetch
        compute(0, kk);
        lwrite(1, bx0, bx1, bb0, bb1);             // tile kk+1 -> LDS1 (waits B-set)
        asm volatile("s_waitcnt lgkmcnt(0)" ::: "memory");
        __builtin_amdgcn_s_barrier();              // LDS1 visible; all done with LDS0

        // tile kk+1: LDS1 current; B-regs free
        gload(kk + 3, bx0, bx1, bb0, bb1);
        compute(1, kk + 1);
        lwrite(0, ax0, ax1, ab0, ab1);             // tile kk+2 -> LDS0 (waits A-set)
        asm volatile("s_waitcnt lgkmcnt(0)" ::: "memory");
        __builtin_amdgcn_s_barrier();              // LDS0 visible
    }

    // ---- epilogue: acc rows are n-contiguous -> float4 stores
    float* dst = part + ((size_t)(b * NH + h) * NBLK + blk) * 4096;
    #pragma unroll
    for (int i = 0; i < 8; ++i) {
        float4 lo = make_float4(acc[i][0], acc[i][1], acc[i][2], acc[i][3]);
        float4 hi = make_float4(acc[i][4], acc[i][5], acc[i][6], acc[i][7]);
        *(float4*)&dst[(p0F + i) * 64 + n0F]     = lo;
        *(float4*)&dst[(p0F + i) * 64 + n0F + 4] = hi;
    }
}

// ---------------------------------------------------------------------------
// k_scales: suffix-exp over chunk totals, per (b,h)
// ---------------------------------------------------------------------------
__global__ void k_scales(const float* __restrict__ blockA, float* __restrict__ scale,
                         int nblk)
{
    const int bh = blockIdx.x * blockDim.x + threadIdx.x;
    if (bh < BATCH * NH) {
        float run = 0.f;
        for (int c2 = nblk - 1; c2 >= 0; --c2) {
            scale[bh * nblk + c2] = __expf(run);
            run += blockA[bh * nblk + c2];
        }
    }
}

// ---------------------------------------------------------------------------
// k_combine: out[bh,p,n] = sum_c scale[bh,c] * part[bh,c,p,n]
// ---------------------------------------------------------------------------
__global__ __launch_bounds__(256)
void k_combine(const float* __restrict__ part, const float* __restrict__ scale,
               float* __restrict__ out, int nblk)
{
    const int idx = blockIdx.x * 256 + threadIdx.x;   // 0..524287
    const int bh  = idx >> 12;
    const int e   = idx & 4095;
    float r = 0.f;
    for (int q = 0; q < nblk; ++q)
        r += scale[bh * nblk + q] * part[((size_t)bh * nblk + q) * 4096 + e];
    out[idx] = r;
}

// ---------------------------------------------------------------------------
extern "C" void kernel_launch(void* const* d_in, const int* in_sizes, int n_in,
                              void* d_out, int out_size, void* d_ws, size_t ws_size,
                              hipStream_t stream)
{
    const float* X = (const float*)d_in[0];
    const float* A = (const float*)d_in[1];
    const float* B = (const float*)d_in[2];
    float* out     = (float*)d_out;

    // ws need for NBLK chunks: part (8*16*NBLK*4096 f32) + blockA + scale
    const size_t need32 = ((size_t)BATCH * NH * 32 * 4096 + 2ull * BATCH * NH * 32) * 4;
    const int nblk = (ws_size >= need32) ? 32 : 16;

    float* part   = (float*)d_ws;
    float* blockA = part + (size_t)BATCH * NH * nblk * 4096;
    float* scale  = blockA + (size_t)BATCH * NH * nblk;

    if (nblk == 32)
        hipLaunchKernelGGL((k_partial<32>), dim3(BATCH * 4 * 32), dim3(NTHR), 0, stream,
                           X, A, B, part, blockA);
    else
        hipLaunchKernelGGL((k_partial<16>), dim3(BATCH * 4 * 16), dim3(NTHR), 0, stream,
                           X, A, B, part, blockA);

    hipLaunchKernelGGL(k_scales, dim3(1), dim3(128), 0, stream, blockA, scale, nblk);
    hipLaunchKernelGGL(k_combine, dim3((BATCH * NH * 4096) / 256), dim3(256), 0, stream,
                       part, scale, out, nblk);
}